// Round 2
// baseline (1306.679 us; speedup 1.0000x reference)
//
#include <hip/hip_runtime.h>

// ---------------- problem constants ----------------
#define N_NODES   100000
#define IN_DIM    256
#define OUT_DIM   256
#define N_REL     8
#define E_PER_REL 160000
#define N_EDGES   (N_REL * E_PER_REL)      // 1,280,000
#define N_COLS    ((N_REL + 1) * OUT_DIM)  // 2304 logical: rel blocks 0..7, self block 8
#define LN_EPS    1e-5f

// column phasing: 4 phases x 64 columns; H chunk holds 9 rel-blocks x 64 cols
#define CPH 64
#define N_PHASE 4
#define HC  (9 * CPH)   // 576 cols per H row

typedef unsigned short ushort_t;
typedef unsigned int   uint_t;

typedef __attribute__((ext_vector_type(8))) __bf16    bf16x8;
typedef __attribute__((ext_vector_type(8))) ushort_t  u16x8;
typedef __attribute__((ext_vector_type(4))) float     f32x4;

__device__ __forceinline__ ushort_t f2bf(float f) {
    uint_t x = __float_as_uint(f);
    x += 0x7FFFu + ((x >> 16) & 1u);   // round-to-nearest-even
    return (ushort_t)(x >> 16);
}
__device__ __forceinline__ float bf2f(ushort_t u) {
    return __uint_as_float(((uint_t)u) << 16);
}

// ---------------- prep: BT[n][k], n = r*256+c (r<8 rel, r==8 self) ----------------
__global__ void prep_w_kernel(const float* __restrict__ Wself, const float* __restrict__ rel,
                              ushort_t* __restrict__ BT) {
    int i = blockIdx.x * 256 + threadIdx.x;   // 0 .. 2304*256-1
    if (i >= N_COLS * IN_DIM) return;
    int n = i >> 8, k = i & 255;
    int r = n >> 8, c = n & 255;
    float v = (r < N_REL) ? rel[(((r << 8) + k) << 8) + c] : Wself[(k << 8) + c];
    BT[i] = f2bf(v);
}

__global__ void zero_kernel(int* __restrict__ p, int n) {
    int i = blockIdx.x * 256 + threadIdx.x;
    if (i < n) p[i] = 0;
}

// ---------------- CSR build ----------------
__global__ void hist_kernel(const int* __restrict__ dst, int* __restrict__ counts, int n) {
    int i = blockIdx.x * 256 + threadIdx.x;
    if (i < n) atomicAdd(&counts[dst[i]], 1);
}

__global__ __launch_bounds__(1024) void scan_kernel(const int* __restrict__ counts,
                                                    int* __restrict__ offsets,
                                                    int* __restrict__ cursor, int n) {
    __shared__ int wsum[16];
    int tid = threadIdx.x, lane = tid & 63, w = tid >> 6;
    int carry = 0;
    for (int base = 0; base < n; base += 1024) {
        int i = base + tid;
        int v = (i < n) ? counts[i] : 0;
        int x = v;
        #pragma unroll
        for (int d = 1; d < 64; d <<= 1) {
            int y = __shfl_up(x, d, 64);
            if (lane >= d) x += y;
        }
        if (lane == 63) wsum[w] = x;
        __syncthreads();
        if (w == 0) {
            int s = (lane < 16) ? wsum[lane] : 0;
            #pragma unroll
            for (int d = 1; d < 16; d <<= 1) {
                int y = __shfl_up(s, d, 64);
                if (lane >= d) s += y;
            }
            if (lane < 16) wsum[lane] = s;
        }
        __syncthreads();
        int wexcl = (w == 0) ? 0 : wsum[w - 1];
        int excl = carry + wexcl + x - v;
        if (i < n) { offsets[i] = excl; cursor[i] = excl; }
        carry += wsum[15];
        __syncthreads();
    }
    if (tid == 0) offsets[n] = carry;
}

__global__ void fill_kernel(const int* __restrict__ src, const int* __restrict__ dst,
                            int* __restrict__ cursor, uint_t* __restrict__ edges, int n) {
    int i = blockIdx.x * 256 + threadIdx.x;
    if (i < n) {
        uint_t rel = (uint_t)i / E_PER_REL;          // 0..7
        int slot = atomicAdd(&cursor[dst[i]], 1);
        edges[slot] = (uint_t)src[i] | (rel << 20);
    }
}

// ---------------- phase GEMM: H[M][576] = x(fp32->bf16)[M][256] @ BT[sel rows][256]^T ----------
// block: 128 rows x 64 cols, 256 threads = 4 waves in 2(M) x 2(N), wave tile 64x32
#define BM 128
#define BN 64
#define BK 64
#define KT 256

__global__ __launch_bounds__(256) void gemm_kernel(const float* __restrict__ X,
                                                   const ushort_t* __restrict__ B,
                                                   ushort_t* __restrict__ H,
                                                   int M, int c0) {
    // XOR-swizzled LDS, 16B granules: granule(row, chunk) = row*8 + (chunk ^ (row&7))
    __shared__ ushort_t As[BM * BK];   // 16 KB
    __shared__ ushort_t Bs[BN * BK];   //  8 KB

    const int m0   = blockIdx.x * BM;
    const int rblk = blockIdx.y;               // 0..8 relation block
    const int nb   = rblk * 256 + c0;          // BT row base for this phase
    const int tid  = threadIdx.x;
    const int lane = tid & 63, w = tid >> 6;
    const int quad = lane >> 4, m16 = lane & 15;
    const int wm = (w & 1) * 64, wn = (w >> 1) * 32;

    f32x4 acc[4][2];
    #pragma unroll
    for (int mi = 0; mi < 4; ++mi)
        #pragma unroll
        for (int ni = 0; ni < 2; ++ni)
            #pragma unroll
            for (int e = 0; e < 4; ++e) acc[mi][ni][e] = 0.f;

    for (int kk = 0; kk < KT; kk += BK) {
        // stage A (fp32 -> bf16): 1024 granules, 4 per thread
        #pragma unroll
        for (int i = 0; i < 4; ++i) {
            int g = i * 256 + tid;
            int r = g >> 3, sc = g & 7, c = sc ^ (r & 7);
            int gr = m0 + r; if (gr >= M) gr = M - 1;
            const float* sp = X + (size_t)gr * KT + kk + c * 8;
            float4 f0 = *(const float4*)sp;
            float4 f1 = *(const float4*)(sp + 4);
            u16x8 v;
            v[0] = f2bf(f0.x); v[1] = f2bf(f0.y); v[2] = f2bf(f0.z); v[3] = f2bf(f0.w);
            v[4] = f2bf(f1.x); v[5] = f2bf(f1.y); v[6] = f2bf(f1.z); v[7] = f2bf(f1.w);
            *(u16x8*)(&As[g * 8]) = v;
        }
        // stage B (bf16): 512 granules, 2 per thread
        #pragma unroll
        for (int i = 0; i < 2; ++i) {
            int g = i * 256 + tid;
            int r = g >> 3, sc = g & 7, c = sc ^ (r & 7);
            *(uint4*)(&Bs[g * 8]) = *(const uint4*)(B + (size_t)(nb + r) * KT + kk + c * 8);
        }
        __syncthreads();

        #pragma unroll
        for (int ks = 0; ks < BK; ks += 32) {
            bf16x8 af[4], bfr[2];
            int chunk = (ks >> 3) + quad;   // 0..7
            #pragma unroll
            for (int mi = 0; mi < 4; ++mi) {
                int row = wm + mi * 16 + m16;
                af[mi] = *(const bf16x8*)(&As[(row * 8 + (chunk ^ (row & 7))) * 8]);
            }
            #pragma unroll
            for (int ni = 0; ni < 2; ++ni) {
                int row = wn + ni * 16 + m16;
                bfr[ni] = *(const bf16x8*)(&Bs[(row * 8 + (chunk ^ (row & 7))) * 8]);
            }
            #pragma unroll
            for (int mi = 0; mi < 4; ++mi)
                #pragma unroll
                for (int ni = 0; ni < 2; ++ni)
                    acc[mi][ni] = __builtin_amdgcn_mfma_f32_16x16x32_bf16(
                        af[mi], bfr[ni], acc[mi][ni], 0, 0, 0);
        }
        __syncthreads();
    }

    // epilogue: C/D layout col = lane&15, row = quad*4 + reg
    #pragma unroll
    for (int mi = 0; mi < 4; ++mi) {
        #pragma unroll
        for (int ni = 0; ni < 2; ++ni) {
            int col = rblk * CPH + wn + ni * 16 + m16;     // H col 0..575
            int rowb = m0 + wm + mi * 16 + quad * 4;
            #pragma unroll
            for (int rg = 0; rg < 4; ++rg) {
                int row = rowb + rg;
                if (row < M) H[(size_t)row * HC + col] = f2bf(acc[mi][ni][rg]);
            }
        }
    }
}

// ---------------- gather phase: one wave per node, one column per lane ----------------
__global__ __launch_bounds__(256) void gather_kernel(const ushort_t* __restrict__ H,
                                                     const int* __restrict__ offs,
                                                     const uint_t* __restrict__ edges,
                                                     float* __restrict__ out, int c0) {
    int w = threadIdx.x >> 6, lane = threadIdx.x & 63;
    int node = blockIdx.x * 4 + w;
    if (node >= N_NODES) return;

    float a = bf2f(H[(size_t)node * HC + 8 * CPH + lane]);   // self block
    int e0 = offs[node], e1 = offs[node + 1];
    int e = e0;
    for (; e + 1 < e1; e += 2) {
        uint_t r0 = edges[e], r1 = edges[e + 1];
        float v0 = bf2f(H[(size_t)(r0 & 0xFFFFFu) * HC + ((r0 >> 20) << 6) + lane]);
        float v1 = bf2f(H[(size_t)(r1 & 0xFFFFFu) * HC + ((r1 >> 20) << 6) + lane]);
        a += v0; a += v1;
    }
    if (e < e1) {
        uint_t r0 = edges[e];
        a += bf2f(H[(size_t)(r0 & 0xFFFFFu) * HC + ((r0 >> 20) << 6) + lane]);
    }
    out[(size_t)node * OUT_DIM + c0 + lane] = a;
}

// ---------------- in-place LayerNorm over d_out ----------------
__global__ __launch_bounds__(256) void ln_kernel(float* __restrict__ out,
                                                 const float* __restrict__ gamma,
                                                 const float* __restrict__ beta) {
    int w = threadIdx.x >> 6, lane = threadIdx.x & 63;
    int node = blockIdx.x * 4 + w;
    if (node >= N_NODES) return;
    int c4 = lane * 4;
    float4 v = *(const float4*)(out + (size_t)node * OUT_DIM + c4);
    float s = v.x + v.y + v.z + v.w;
    float q = v.x * v.x + v.y * v.y + v.z * v.z + v.w * v.w;
    #pragma unroll
    for (int off = 32; off > 0; off >>= 1) {
        s += __shfl_xor(s, off, 64);
        q += __shfl_xor(q, off, 64);
    }
    float mean = s * (1.f / 256.f);
    float var  = q * (1.f / 256.f) - mean * mean;
    float rstd = rsqrtf(var + LN_EPS);
    float4 g = *(const float4*)(gamma + c4);
    float4 b = *(const float4*)(beta + c4);
    float4 o;
    o.x = (v.x - mean) * rstd * g.x + b.x;
    o.y = (v.y - mean) * rstd * g.y + b.y;
    o.z = (v.z - mean) * rstd * g.z + b.z;
    o.w = (v.w - mean) * rstd * g.w + b.w;
    *(float4*)(out + (size_t)node * OUT_DIM + c4) = o;
}

// ---------------- launch ----------------
extern "C" void kernel_launch(void* const* d_in, const int* in_sizes, int n_in,
                              void* d_out, int out_size, void* d_ws, size_t ws_size,
                              hipStream_t stream) {
    const float* x     = (const float*)d_in[0];
    const int*   src   = (const int*)d_in[1];
    const int*   dst   = (const int*)d_in[2];
    const float* Wself = (const float*)d_in[3];
    const float* rel   = (const float*)d_in[4];
    const float* gamma = (const float*)d_in[5];
    const float* beta  = (const float*)d_in[6];
    float* out = (float*)d_out;

    // workspace layout — total ~122.7 MB
    char* ws = (char*)d_ws;
    constexpr size_t BT_OFF   = 0;                                    // 1,179,648 B
    constexpr size_t H_OFF    = BT_OFF + (size_t)N_COLS * IN_DIM * 2;
    constexpr size_t CNT_OFF  = H_OFF + (size_t)N_NODES * HC * 2;     // +115,200,000
    constexpr size_t OFFS_OFF = CNT_OFF + 400128;
    constexpr size_t CUR_OFF  = OFFS_OFF + 400128;
    constexpr size_t EDGE_OFF = CUR_OFF + 400128;                     // edges: 5,120,000 B

    ushort_t* BT     = (ushort_t*)(ws + BT_OFF);
    ushort_t* H      = (ushort_t*)(ws + H_OFF);
    int*      counts = (int*)(ws + CNT_OFF);
    int*      offs   = (int*)(ws + OFFS_OFF);
    int*      cursor = (int*)(ws + CUR_OFF);
    uint_t*   edges  = (uint_t*)(ws + EDGE_OFF);

    prep_w_kernel<<<(N_COLS * IN_DIM + 255) / 256, 256, 0, stream>>>(Wself, rel, BT);
    zero_kernel<<<(N_NODES + 255) / 256, 256, 0, stream>>>(counts, N_NODES);
    hist_kernel<<<(N_EDGES + 255) / 256, 256, 0, stream>>>(dst, counts, N_EDGES);
    scan_kernel<<<1, 1024, 0, stream>>>(counts, offs, cursor, N_NODES);
    fill_kernel<<<(N_EDGES + 255) / 256, 256, 0, stream>>>(src, dst, cursor, edges, N_EDGES);

    dim3 ggrid((N_NODES + BM - 1) / BM, 9);
    for (int p = 0; p < N_PHASE; ++p) {
        int c0 = p * CPH;
        gemm_kernel<<<ggrid, 256, 0, stream>>>(x, BT, H, N_NODES, c0);
        gather_kernel<<<(N_NODES + 3) / 4, 256, 0, stream>>>(H, offs, edges, out, c0);
    }
    ln_kernel<<<(N_NODES + 3) / 4, 256, 0, stream>>>(out, gamma, beta);
}

// Round 3
// 951.516 us; speedup vs baseline: 1.3733x; 1.3733x over previous
//
#include <hip/hip_runtime.h>
#include <hip/hip_bf16.h>

// ---------------- problem constants ----------------
#define N_NODES   100000
#define IN_DIM    256
#define OUT_DIM   256
#define N_REL     8
#define E_PER_REL 160000
#define N_EDGES   (N_REL * E_PER_REL)      // 1,280,000
#define N_COLS    ((N_REL + 1) * OUT_DIM)  // 2304 logical: rel blocks 0..7, self block 8
#define LN_EPS    1e-5f

// column phasing: 4 phases x 64 columns; H chunk holds 9 rel-blocks x 64 cols
#define CPH 64
#define N_PHASE 4
#define HC  (9 * CPH)   // 576 cols per H row

typedef unsigned short ushort_t;
typedef unsigned int   uint_t;

typedef __attribute__((ext_vector_type(8))) __bf16    bf16x8;
typedef __attribute__((ext_vector_type(4))) float     f32x4;

__device__ __forceinline__ ushort_t f2bf(float f) {
    uint_t x = __float_as_uint(f);
    x += 0x7FFFu + ((x >> 16) & 1u);   // round-to-nearest-even
    return (ushort_t)(x >> 16);
}
__device__ __forceinline__ float bf2f(ushort_t u) {
    return __uint_as_float(((uint_t)u) << 16);
}

// ---------------- prep: BT[n][k], n = r*256+c (r<8 rel, r==8 self) ----------------
__global__ void prep_w_kernel(const float* __restrict__ Wself, const float* __restrict__ rel,
                              ushort_t* __restrict__ BT) {
    int i = blockIdx.x * 256 + threadIdx.x;   // 0 .. 2304*256-1
    if (i >= N_COLS * IN_DIM) return;
    int n = i >> 8, k = i & 255;
    int r = n >> 8, c = n & 255;
    float v = (r < N_REL) ? rel[(((r << 8) + k) << 8) + c] : Wself[(k << 8) + c];
    BT[i] = f2bf(v);
}

__global__ void zero_kernel(int* __restrict__ p, int n) {
    int i = blockIdx.x * 256 + threadIdx.x;
    if (i < n) p[i] = 0;
}

// ---------------- CSR build ----------------
__global__ void hist_kernel(const int* __restrict__ dst, int* __restrict__ counts, int n) {
    int i = blockIdx.x * 256 + threadIdx.x;
    if (i < n) atomicAdd(&counts[dst[i]], 1);
}

__global__ __launch_bounds__(1024) void scan_kernel(const int* __restrict__ counts,
                                                    int* __restrict__ offsets,
                                                    int* __restrict__ cursor, int n) {
    __shared__ int wsum[16];
    int tid = threadIdx.x, lane = tid & 63, w = tid >> 6;
    int carry = 0;
    for (int base = 0; base < n; base += 1024) {
        int i = base + tid;
        int v = (i < n) ? counts[i] : 0;
        int x = v;
        #pragma unroll
        for (int d = 1; d < 64; d <<= 1) {
            int y = __shfl_up(x, d, 64);
            if (lane >= d) x += y;
        }
        if (lane == 63) wsum[w] = x;
        __syncthreads();
        if (w == 0) {
            int s = (lane < 16) ? wsum[lane] : 0;
            #pragma unroll
            for (int d = 1; d < 16; d <<= 1) {
                int y = __shfl_up(s, d, 64);
                if (lane >= d) s += y;
            }
            if (lane < 16) wsum[lane] = s;
        }
        __syncthreads();
        int wexcl = (w == 0) ? 0 : wsum[w - 1];
        int excl = carry + wexcl + x - v;
        if (i < n) { offsets[i] = excl; cursor[i] = excl; }
        carry += wsum[15];
        __syncthreads();
    }
    if (tid == 0) offsets[n] = carry;
}

__global__ void fill_kernel(const int* __restrict__ src, const int* __restrict__ dst,
                            int* __restrict__ cursor, uint_t* __restrict__ edges, int n) {
    int i = blockIdx.x * 256 + threadIdx.x;
    if (i < n) {
        uint_t rel = (uint_t)i / E_PER_REL;          // 0..7
        int slot = atomicAdd(&cursor[dst[i]], 1);
        edges[slot] = (uint_t)src[i] | (rel << 20);
    }
}

// ---------------- phase GEMM: H[M][576] = x(fp32->bf16)[M][256] @ BT[sel rows][256]^T ----------
// block: 128 rows x 3 rel-blocks x 64 cols. A staged once per kk, reused for 3 B tiles.
#define BM 128
#define BN 64
#define BK 64
#define KT 256
#define RB 3

__global__ __launch_bounds__(256) void gemm_kernel(const float* __restrict__ X,
                                                   const ushort_t* __restrict__ B,
                                                   ushort_t* __restrict__ H,
                                                   int M, int c0) {
    // XOR-swizzled LDS, 16B granules: granule(row, chunk) = row*8 + (chunk ^ (row&7))
    __shared__ ushort_t As[BM * BK];        // 16 KB
    __shared__ ushort_t Bs[RB][BN * BK];    // 24 KB

    const int rb0 = blockIdx.x * RB;        // rel blocks rb0..rb0+2 (grid.x = 3 -> 0..8)
    const int m0  = blockIdx.y * BM;
    const int tid  = threadIdx.x;
    const int lane = tid & 63, w = tid >> 6;
    const int quad = lane >> 4, m16 = lane & 15;
    const int wm = (w & 1) * 64, wn = (w >> 1) * 32;

    f32x4 acc[RB][4][2];
    #pragma unroll
    for (int t = 0; t < RB; ++t)
        #pragma unroll
        for (int mi = 0; mi < 4; ++mi)
            #pragma unroll
            for (int ni = 0; ni < 2; ++ni)
                #pragma unroll
                for (int e = 0; e < 4; ++e) acc[t][mi][ni][e] = 0.f;

    for (int kk = 0; kk < KT; kk += BK) {
        // stage A (fp32 -> bf16, packed cvt): 1024 granules, 4 per thread
        #pragma unroll
        for (int i = 0; i < 4; ++i) {
            int g = i * 256 + tid;
            int r = g >> 3, sc = g & 7, c = sc ^ (r & 7);
            int gr = m0 + r; if (gr >= M) gr = M - 1;
            const float* sp = X + (size_t)gr * KT + kk + c * 8;
            float4 f0 = *(const float4*)sp;
            float4 f1 = *(const float4*)(sp + 4);
            __hip_bfloat162 h0 = __float22bfloat162_rn(make_float2(f0.x, f0.y));
            __hip_bfloat162 h1 = __float22bfloat162_rn(make_float2(f0.z, f0.w));
            __hip_bfloat162 h2 = __float22bfloat162_rn(make_float2(f1.x, f1.y));
            __hip_bfloat162 h3 = __float22bfloat162_rn(make_float2(f1.z, f1.w));
            uint4 pv;
            __builtin_memcpy(&pv.x, &h0, 4);
            __builtin_memcpy(&pv.y, &h1, 4);
            __builtin_memcpy(&pv.z, &h2, 4);
            __builtin_memcpy(&pv.w, &h3, 4);
            *(uint4*)(&As[g * 8]) = pv;
        }
        // stage B tiles (bf16): 512 granules x 3, 2 per thread per tile
        #pragma unroll
        for (int t = 0; t < RB; ++t) {
            #pragma unroll
            for (int i = 0; i < 2; ++i) {
                int g = i * 256 + tid;
                int r = g >> 3, sc = g & 7, c = sc ^ (r & 7);
                int nrow = (rb0 + t) * 256 + c0 + r;
                *(uint4*)(&Bs[t][g * 8]) = *(const uint4*)(B + (size_t)nrow * KT + kk + c * 8);
            }
        }
        __syncthreads();

        #pragma unroll
        for (int ks = 0; ks < BK; ks += 32) {
            int chunk = (ks >> 3) + quad;   // 0..7
            bf16x8 af[4];
            #pragma unroll
            for (int mi = 0; mi < 4; ++mi) {
                int row = wm + mi * 16 + m16;
                af[mi] = *(const bf16x8*)(&As[(row * 8 + (chunk ^ (row & 7))) * 8]);
            }
            #pragma unroll
            for (int t = 0; t < RB; ++t) {
                bf16x8 bfr[2];
                #pragma unroll
                for (int ni = 0; ni < 2; ++ni) {
                    int row = wn + ni * 16 + m16;
                    bfr[ni] = *(const bf16x8*)(&Bs[t][(row * 8 + (chunk ^ (row & 7))) * 8]);
                }
                #pragma unroll
                for (int mi = 0; mi < 4; ++mi)
                    #pragma unroll
                    for (int ni = 0; ni < 2; ++ni)
                        acc[t][mi][ni] = __builtin_amdgcn_mfma_f32_16x16x32_bf16(
                            af[mi], bfr[ni], acc[t][mi][ni], 0, 0, 0);
            }
        }
        __syncthreads();
    }

    // epilogue: C/D layout col = lane&15, row = quad*4 + reg
    #pragma unroll
    for (int t = 0; t < RB; ++t) {
        #pragma unroll
        for (int mi = 0; mi < 4; ++mi) {
            #pragma unroll
            for (int ni = 0; ni < 2; ++ni) {
                int col = (rb0 + t) * CPH + wn + ni * 16 + m16;   // H col 0..575
                int rowb = m0 + wm + mi * 16 + quad * 4;
                #pragma unroll
                for (int rg = 0; rg < 4; ++rg) {
                    int row = rowb + rg;
                    if (row < M) H[(size_t)row * HC + col] = f2bf(acc[t][mi][ni][rg]);
                }
            }
        }
    }
}

// ---------------- gather phase: one wave per node, 16 lanes x 4 cols per edge slot -----------
__global__ __launch_bounds__(256) void gather_kernel(const ushort_t* __restrict__ H,
                                                     const int* __restrict__ offs,
                                                     const uint_t* __restrict__ edges,
                                                     float* __restrict__ out, int c0) {
    int w = threadIdx.x >> 6, lane = threadIdx.x & 63;
    int node = blockIdx.x * 4 + w;
    if (node >= N_NODES) return;
    int grp = lane >> 4;          // edge slot 0..3
    int cs  = (lane & 15) * 4;    // col offset 0..60

    float4 a = make_float4(0.f, 0.f, 0.f, 0.f);
    if (grp == 0) {   // self block (col base 8*CPH = 512), counted once
        ushort4 v = *(const ushort4*)(H + (size_t)node * HC + 512 + cs);
        a.x = bf2f(v.x); a.y = bf2f(v.y); a.z = bf2f(v.z); a.w = bf2f(v.w);
    }
    int e0 = offs[node], e1 = offs[node + 1];
    for (int base = e0; base < e1; base += 8) {
        int i0 = base + grp, i1 = base + 4 + grp;
        if (i0 < e1) {
            uint_t r = edges[i0];
            ushort4 v = *(const ushort4*)(H + (size_t)(r & 0xFFFFFu) * HC + ((r >> 20) << 6) + cs);
            a.x += bf2f(v.x); a.y += bf2f(v.y); a.z += bf2f(v.z); a.w += bf2f(v.w);
        }
        if (i1 < e1) {
            uint_t r = edges[i1];
            ushort4 v = *(const ushort4*)(H + (size_t)(r & 0xFFFFFu) * HC + ((r >> 20) << 6) + cs);
            a.x += bf2f(v.x); a.y += bf2f(v.y); a.z += bf2f(v.z); a.w += bf2f(v.w);
        }
    }
    // combine 4 edge-slot groups: xor over 16 and 32
    #pragma unroll
    for (int off = 16; off <= 32; off <<= 1) {
        a.x += __shfl_xor(a.x, off, 64);
        a.y += __shfl_xor(a.y, off, 64);
        a.z += __shfl_xor(a.z, off, 64);
        a.w += __shfl_xor(a.w, off, 64);
    }
    if (grp == 0)
        *(float4*)(out + (size_t)node * OUT_DIM + c0 + cs) = a;
}

// ---------------- in-place LayerNorm over d_out ----------------
__global__ __launch_bounds__(256) void ln_kernel(float* __restrict__ out,
                                                 const float* __restrict__ gamma,
                                                 const float* __restrict__ beta) {
    int w = threadIdx.x >> 6, lane = threadIdx.x & 63;
    int node = blockIdx.x * 4 + w;
    if (node >= N_NODES) return;
    int c4 = lane * 4;
    float4 v = *(const float4*)(out + (size_t)node * OUT_DIM + c4);
    float s = v.x + v.y + v.z + v.w;
    float q = v.x * v.x + v.y * v.y + v.z * v.z + v.w * v.w;
    #pragma unroll
    for (int off = 32; off > 0; off >>= 1) {
        s += __shfl_xor(s, off, 64);
        q += __shfl_xor(q, off, 64);
    }
    float mean = s * (1.f / 256.f);
    float var  = q * (1.f / 256.f) - mean * mean;
    float rstd = rsqrtf(var + LN_EPS);
    float4 g = *(const float4*)(gamma + c4);
    float4 b = *(const float4*)(beta + c4);
    float4 o;
    o.x = (v.x - mean) * rstd * g.x + b.x;
    o.y = (v.y - mean) * rstd * g.y + b.y;
    o.z = (v.z - mean) * rstd * g.z + b.z;
    o.w = (v.w - mean) * rstd * g.w + b.w;
    *(float4*)(out + (size_t)node * OUT_DIM + c4) = o;
}

// ---------------- launch ----------------
extern "C" void kernel_launch(void* const* d_in, const int* in_sizes, int n_in,
                              void* d_out, int out_size, void* d_ws, size_t ws_size,
                              hipStream_t stream) {
    const float* x     = (const float*)d_in[0];
    const int*   src   = (const int*)d_in[1];
    const int*   dst   = (const int*)d_in[2];
    const float* Wself = (const float*)d_in[3];
    const float* rel   = (const float*)d_in[4];
    const float* gamma = (const float*)d_in[5];
    const float* beta  = (const float*)d_in[6];
    float* out = (float*)d_out;

    // workspace layout — total ~122.7 MB
    char* ws = (char*)d_ws;
    constexpr size_t BT_OFF   = 0;                                    // 1,179,648 B
    constexpr size_t H_OFF    = BT_OFF + (size_t)N_COLS * IN_DIM * 2;
    constexpr size_t CNT_OFF  = H_OFF + (size_t)N_NODES * HC * 2;     // +115,200,000
    constexpr size_t OFFS_OFF = CNT_OFF + 400128;
    constexpr size_t CUR_OFF  = OFFS_OFF + 400128;
    constexpr size_t EDGE_OFF = CUR_OFF + 400128;                     // edges: 5,120,000 B

    ushort_t* BT     = (ushort_t*)(ws + BT_OFF);
    ushort_t* H      = (ushort_t*)(ws + H_OFF);
    int*      counts = (int*)(ws + CNT_OFF);
    int*      offs   = (int*)(ws + OFFS_OFF);
    int*      cursor = (int*)(ws + CUR_OFF);
    uint_t*   edges  = (uint_t*)(ws + EDGE_OFF);

    prep_w_kernel<<<(N_COLS * IN_DIM + 255) / 256, 256, 0, stream>>>(Wself, rel, BT);
    zero_kernel<<<(N_NODES + 255) / 256, 256, 0, stream>>>(counts, N_NODES);
    hist_kernel<<<(N_EDGES + 255) / 256, 256, 0, stream>>>(dst, counts, N_EDGES);
    scan_kernel<<<1, 1024, 0, stream>>>(counts, offs, cursor, N_NODES);
    fill_kernel<<<(N_EDGES + 255) / 256, 256, 0, stream>>>(src, dst, cursor, edges, N_EDGES);

    dim3 ggrid(3, (N_NODES + BM - 1) / BM);   // rel-block triple fastest; A stripe reused in L3
    for (int p = 0; p < N_PHASE; ++p) {
        int c0 = p * CPH;
        gemm_kernel<<<ggrid, 256, 0, stream>>>(x, BT, H, N_NODES, c0);
        gather_kernel<<<(N_NODES + 3) / 4, 256, 0, stream>>>(H, offs, edges, out, c0);
    }
    ln_kernel<<<(N_NODES + 3) / 4, 256, 0, stream>>>(out, gamma, beta);
}

// Round 4
// 870.029 us; speedup vs baseline: 1.5019x; 1.0937x over previous
//
#include <hip/hip_runtime.h>
#include <hip/hip_bf16.h>

// ---------------- problem constants ----------------
#define N_NODES   100000
#define IN_DIM    256
#define OUT_DIM   256
#define N_REL     8
#define E_PER_REL 160000
#define N_EDGES   (N_REL * E_PER_REL)      // 1,280,000
#define N_COLS    ((N_REL + 1) * OUT_DIM)  // 2304 logical: rel blocks 0..7, self block 8
#define LN_EPS    1e-5f

// column phasing: 4 phases x 64 columns; H chunk holds 9 rel-blocks x 64 cols
#define CPH 64
#define N_PHASE 4
#define HC  (9 * CPH)   // 576 cols per H row

typedef unsigned short ushort_t;
typedef unsigned int   uint_t;

typedef __attribute__((ext_vector_type(8))) __bf16    bf16x8;
typedef __attribute__((ext_vector_type(4))) float     f32x4;

__device__ __forceinline__ ushort_t f2bf(float f) {
    uint_t x = __float_as_uint(f);
    x += 0x7FFFu + ((x >> 16) & 1u);   // round-to-nearest-even
    return (ushort_t)(x >> 16);
}
__device__ __forceinline__ float bf_lo(uint_t u) { return __uint_as_float(u << 16); }
__device__ __forceinline__ float bf_hi(uint_t u) { return __uint_as_float(u & 0xFFFF0000u); }

// ---------------- x fp32 -> bf16 (once) ----------------
__global__ void conv_x_kernel(const float* __restrict__ x, ushort_t* __restrict__ xb) {
    int i = blockIdx.x * 256 + threadIdx.x;         // one per 8 elements
    if (i >= N_NODES * IN_DIM / 8) return;
    const float4* p = (const float4*)x + (size_t)i * 2;
    float4 f0 = p[0], f1 = p[1];
    __hip_bfloat162 h0 = __float22bfloat162_rn(make_float2(f0.x, f0.y));
    __hip_bfloat162 h1 = __float22bfloat162_rn(make_float2(f0.z, f0.w));
    __hip_bfloat162 h2 = __float22bfloat162_rn(make_float2(f1.x, f1.y));
    __hip_bfloat162 h3 = __float22bfloat162_rn(make_float2(f1.z, f1.w));
    uint4 pv;
    __builtin_memcpy(&pv.x, &h0, 4);
    __builtin_memcpy(&pv.y, &h1, 4);
    __builtin_memcpy(&pv.z, &h2, 4);
    __builtin_memcpy(&pv.w, &h3, 4);
    *(uint4*)(xb + (size_t)i * 8) = pv;
}

// ---------------- prep: BT[n][k], n = r*256+c (r<8 rel, r==8 self) ----------------
__global__ void prep_w_kernel(const float* __restrict__ Wself, const float* __restrict__ rel,
                              ushort_t* __restrict__ BT) {
    int i = blockIdx.x * 256 + threadIdx.x;   // 0 .. 2304*256-1
    if (i >= N_COLS * IN_DIM) return;
    int n = i >> 8, k = i & 255;
    int r = n >> 8, c = n & 255;
    float v = (r < N_REL) ? rel[(((r << 8) + k) << 8) + c] : Wself[(k << 8) + c];
    BT[i] = f2bf(v);
}

// ---------------- CSR build ----------------
__global__ void hist_kernel(const int* __restrict__ dst, int* __restrict__ counts) {
    int base = (blockIdx.x * 256 + threadIdx.x) * 4;
    if (base < N_EDGES) {
        int4 d = *(const int4*)(dst + base);
        atomicAdd(&counts[d.x], 1);
        atomicAdd(&counts[d.y], 1);
        atomicAdd(&counts[d.z], 1);
        atomicAdd(&counts[d.w], 1);
    }
}

__global__ __launch_bounds__(1024) void scan_kernel(const int* __restrict__ counts,
                                                    int* __restrict__ offsets,
                                                    int* __restrict__ cursor, int n) {
    __shared__ int wsum[16];
    int tid = threadIdx.x, lane = tid & 63, w = tid >> 6;
    int carry = 0;
    for (int base = 0; base < n; base += 1024) {
        int i = base + tid;
        int v = (i < n) ? counts[i] : 0;
        int x = v;
        #pragma unroll
        for (int d = 1; d < 64; d <<= 1) {
            int y = __shfl_up(x, d, 64);
            if (lane >= d) x += y;
        }
        if (lane == 63) wsum[w] = x;
        __syncthreads();
        if (w == 0) {
            int s = (lane < 16) ? wsum[lane] : 0;
            #pragma unroll
            for (int d = 1; d < 16; d <<= 1) {
                int y = __shfl_up(s, d, 64);
                if (lane >= d) s += y;
            }
            if (lane < 16) wsum[lane] = s;
        }
        __syncthreads();
        int wexcl = (w == 0) ? 0 : wsum[w - 1];
        int excl = carry + wexcl + x - v;
        if (i < n) { offsets[i] = excl; cursor[i] = excl; }
        carry += wsum[15];
        __syncthreads();
    }
    if (tid == 0) offsets[n] = carry;
}

__global__ void fill_kernel(const int* __restrict__ src, const int* __restrict__ dst,
                            int* __restrict__ cursor, uint_t* __restrict__ edges) {
    int base = (blockIdx.x * 256 + threadIdx.x) * 4;
    if (base >= N_EDGES) return;
    int4 s = *(const int4*)(src + base);
    int4 d = *(const int4*)(dst + base);
    uint_t rel = ((uint_t)base / E_PER_REL) << 20;   // E_PER_REL % 4 == 0 -> uniform per quad
    int s0 = atomicAdd(&cursor[d.x], 1); edges[s0] = (uint_t)s.x | rel;
    int s1 = atomicAdd(&cursor[d.y], 1); edges[s1] = (uint_t)s.y | rel;
    int s2 = atomicAdd(&cursor[d.z], 1); edges[s2] = (uint_t)s.z | rel;
    int s3 = atomicAdd(&cursor[d.w], 1); edges[s3] = (uint_t)s.w | rel;
}

// ---------------- phase GEMM: H[M][576] = X[M][256] @ BT[sel rows][256]^T ----------
// block: 128 rows x 3 rel-blocks x 64 cols. A staged once per kk, reused for 3 B tiles.
#define BM 128
#define BN 64
#define BK 64
#define KT 256
#define RB 3

template <bool BF16X>
__global__ __launch_bounds__(256) void gemm_kernel(const void* __restrict__ Xv,
                                                   const ushort_t* __restrict__ B,
                                                   ushort_t* __restrict__ H,
                                                   int M, int c0) {
    // XOR-swizzled LDS, 16B granules: granule(row, chunk) = row*8 + (chunk ^ (row&7))
    __shared__ ushort_t As[BM * BK];        // 16 KB
    __shared__ ushort_t Bs[RB][BN * BK];    // 24 KB

    const int rb0 = blockIdx.x * RB;        // rel blocks rb0..rb0+2 (grid.x = 3 -> 0..8)
    const int m0  = blockIdx.y * BM;
    const int tid  = threadIdx.x;
    const int lane = tid & 63, w = tid >> 6;
    const int quad = lane >> 4, m16 = lane & 15;
    const int wm = (w & 1) * 64, wn = (w >> 1) * 32;

    f32x4 acc[RB][4][2];
    #pragma unroll
    for (int t = 0; t < RB; ++t)
        #pragma unroll
        for (int mi = 0; mi < 4; ++mi)
            #pragma unroll
            for (int ni = 0; ni < 2; ++ni)
                #pragma unroll
                for (int e = 0; e < 4; ++e) acc[t][mi][ni][e] = 0.f;

    for (int kk = 0; kk < KT; kk += BK) {
        // stage A: 1024 granules, 4 per thread
        #pragma unroll
        for (int i = 0; i < 4; ++i) {
            int g = i * 256 + tid;
            int r = g >> 3, sc = g & 7, c = sc ^ (r & 7);
            int gr = m0 + r; if (gr >= M) gr = M - 1;
            if (BF16X) {
                const ushort_t* X = (const ushort_t*)Xv;
                *(uint4*)(&As[g * 8]) = *(const uint4*)(X + (size_t)gr * KT + kk + c * 8);
            } else {
                const float* X = (const float*)Xv;
                const float* sp = X + (size_t)gr * KT + kk + c * 8;
                float4 f0 = *(const float4*)sp;
                float4 f1 = *(const float4*)(sp + 4);
                __hip_bfloat162 h0 = __float22bfloat162_rn(make_float2(f0.x, f0.y));
                __hip_bfloat162 h1 = __float22bfloat162_rn(make_float2(f0.z, f0.w));
                __hip_bfloat162 h2 = __float22bfloat162_rn(make_float2(f1.x, f1.y));
                __hip_bfloat162 h3 = __float22bfloat162_rn(make_float2(f1.z, f1.w));
                uint4 pv;
                __builtin_memcpy(&pv.x, &h0, 4);
                __builtin_memcpy(&pv.y, &h1, 4);
                __builtin_memcpy(&pv.z, &h2, 4);
                __builtin_memcpy(&pv.w, &h3, 4);
                *(uint4*)(&As[g * 8]) = pv;
            }
        }
        // stage B tiles (bf16): 512 granules x 3, 2 per thread per tile
        #pragma unroll
        for (int t = 0; t < RB; ++t) {
            #pragma unroll
            for (int i = 0; i < 2; ++i) {
                int g = i * 256 + tid;
                int r = g >> 3, sc = g & 7, c = sc ^ (r & 7);
                int nrow = (rb0 + t) * 256 + c0 + r;
                *(uint4*)(&Bs[t][g * 8]) = *(const uint4*)(B + (size_t)nrow * KT + kk + c * 8);
            }
        }
        __syncthreads();

        #pragma unroll
        for (int ks = 0; ks < BK; ks += 32) {
            int chunk = (ks >> 3) + quad;   // 0..7
            bf16x8 af[4];
            #pragma unroll
            for (int mi = 0; mi < 4; ++mi) {
                int row = wm + mi * 16 + m16;
                af[mi] = *(const bf16x8*)(&As[(row * 8 + (chunk ^ (row & 7))) * 8]);
            }
            #pragma unroll
            for (int t = 0; t < RB; ++t) {
                bf16x8 bfr[2];
                #pragma unroll
                for (int ni = 0; ni < 2; ++ni) {
                    int row = wn + ni * 16 + m16;
                    bfr[ni] = *(const bf16x8*)(&Bs[t][(row * 8 + (chunk ^ (row & 7))) * 8]);
                }
                #pragma unroll
                for (int mi = 0; mi < 4; ++mi)
                    #pragma unroll
                    for (int ni = 0; ni < 2; ++ni)
                        acc[t][mi][ni] = __builtin_amdgcn_mfma_f32_16x16x32_bf16(
                            af[mi], bfr[ni], acc[t][mi][ni], 0, 0, 0);
            }
        }
        __syncthreads();
    }

    // epilogue: C/D layout col = lane&15, row = quad*4 + reg
    #pragma unroll
    for (int t = 0; t < RB; ++t) {
        #pragma unroll
        for (int mi = 0; mi < 4; ++mi) {
            #pragma unroll
            for (int ni = 0; ni < 2; ++ni) {
                int col = (rb0 + t) * CPH + wn + ni * 16 + m16;   // H col 0..575
                int rowb = m0 + wm + mi * 16 + quad * 4;
                #pragma unroll
                for (int rg = 0; rg < 4; ++rg) {
                    int row = rowb + rg;
                    if (row < M) H[(size_t)row * HC + col] = f2bf(acc[t][mi][ni][rg]);
                }
            }
        }
    }
}

// ---------------- gather phase: one wave per node, 8 lanes x 16B per edge slot ----------
__global__ __launch_bounds__(256) void gather_kernel(const ushort_t* __restrict__ H,
                                                     const int* __restrict__ offs,
                                                     const uint_t* __restrict__ edges,
                                                     float* __restrict__ out, int c0) {
    int w = threadIdx.x >> 6, lane = threadIdx.x & 63;
    int node = blockIdx.x * 4 + w;
    if (node >= N_NODES) return;
    int grp = lane >> 3;          // edge slot 0..7
    int cs  = (lane & 7) * 8;     // col offset 0..56

    float a0 = 0.f, a1 = 0.f, a2 = 0.f, a3 = 0.f, a4 = 0.f, a5 = 0.f, a6 = 0.f, a7 = 0.f;
    if (grp == 7) {   // self block (col base 8*CPH = 512), counted once
        uint4 v = *(const uint4*)(H + (size_t)node * HC + 512 + cs);
        a0 += bf_lo(v.x); a1 += bf_hi(v.x); a2 += bf_lo(v.y); a3 += bf_hi(v.y);
        a4 += bf_lo(v.z); a5 += bf_hi(v.z); a6 += bf_lo(v.w); a7 += bf_hi(v.w);
    }
    int e0 = offs[node], e1 = offs[node + 1];
    for (int base = e0; base < e1; base += 16) {
        int i0 = base + grp, i1 = base + 8 + grp;
        if (i0 < e1) {
            uint_t r = edges[i0];
            uint4 v = *(const uint4*)(H + (size_t)(r & 0xFFFFFu) * HC + ((r >> 20) << 6) + cs);
            a0 += bf_lo(v.x); a1 += bf_hi(v.x); a2 += bf_lo(v.y); a3 += bf_hi(v.y);
            a4 += bf_lo(v.z); a5 += bf_hi(v.z); a6 += bf_lo(v.w); a7 += bf_hi(v.w);
        }
        if (i1 < e1) {
            uint_t r = edges[i1];
            uint4 v = *(const uint4*)(H + (size_t)(r & 0xFFFFFu) * HC + ((r >> 20) << 6) + cs);
            a0 += bf_lo(v.x); a1 += bf_hi(v.x); a2 += bf_lo(v.y); a3 += bf_hi(v.y);
            a4 += bf_lo(v.z); a5 += bf_hi(v.z); a6 += bf_lo(v.w); a7 += bf_hi(v.w);
        }
    }
    // combine 8 edge-slot groups: xor over 8, 16, 32
    #pragma unroll
    for (int off = 8; off <= 32; off <<= 1) {
        a0 += __shfl_xor(a0, off, 64); a1 += __shfl_xor(a1, off, 64);
        a2 += __shfl_xor(a2, off, 64); a3 += __shfl_xor(a3, off, 64);
        a4 += __shfl_xor(a4, off, 64); a5 += __shfl_xor(a5, off, 64);
        a6 += __shfl_xor(a6, off, 64); a7 += __shfl_xor(a7, off, 64);
    }
    if (grp == 0) {
        float* op = out + (size_t)node * OUT_DIM + c0 + cs;
        *(float4*)op       = make_float4(a0, a1, a2, a3);
        *(float4*)(op + 4) = make_float4(a4, a5, a6, a7);
    }
}

// ---------------- in-place LayerNorm over d_out ----------------
__global__ __launch_bounds__(256) void ln_kernel(float* __restrict__ out,
                                                 const float* __restrict__ gamma,
                                                 const float* __restrict__ beta) {
    int w = threadIdx.x >> 6, lane = threadIdx.x & 63;
    int node = blockIdx.x * 4 + w;
    if (node >= N_NODES) return;
    int c4 = lane * 4;
    float4 v = *(const float4*)(out + (size_t)node * OUT_DIM + c4);
    float s = v.x + v.y + v.z + v.w;
    float q = v.x * v.x + v.y * v.y + v.z * v.z + v.w * v.w;
    #pragma unroll
    for (int off = 32; off > 0; off >>= 1) {
        s += __shfl_xor(s, off, 64);
        q += __shfl_xor(q, off, 64);
    }
    float mean = s * (1.f / 256.f);
    float var  = q * (1.f / 256.f) - mean * mean;
    float rstd = rsqrtf(var + LN_EPS);
    float4 g = *(const float4*)(gamma + c4);
    float4 b = *(const float4*)(beta + c4);
    float4 o;
    o.x = (v.x - mean) * rstd * g.x + b.x;
    o.y = (v.y - mean) * rstd * g.y + b.y;
    o.z = (v.z - mean) * rstd * g.z + b.z;
    o.w = (v.w - mean) * rstd * g.w + b.w;
    *(float4*)(out + (size_t)node * OUT_DIM + c4) = o;
}

// ---------------- launch ----------------
extern "C" void kernel_launch(void* const* d_in, const int* in_sizes, int n_in,
                              void* d_out, int out_size, void* d_ws, size_t ws_size,
                              hipStream_t stream) {
    const float* x     = (const float*)d_in[0];
    const int*   src   = (const int*)d_in[1];
    const int*   dst   = (const int*)d_in[2];
    const float* Wself = (const float*)d_in[3];
    const float* rel   = (const float*)d_in[4];
    const float* gamma = (const float*)d_in[5];
    const float* beta  = (const float*)d_in[6];
    float* out = (float*)d_out;

    char* ws = (char*)d_ws;
    constexpr size_t BT_BYTES   = (size_t)N_COLS * IN_DIM * 2;      // 1,179,648
    constexpr size_t XB_BYTES   = (size_t)N_NODES * IN_DIM * 2;     // 51,200,000
    constexpr size_t H_BYTES    = (size_t)N_NODES * HC * 2;         // 115,200,000
    constexpr size_t CSR_BYTES  = 400128;
    constexpr size_t EDGE_BYTES = (size_t)N_EDGES * 4;              // 5,120,000
    constexpr size_t NEED_A = BT_BYTES + XB_BYTES + H_BYTES + 3 * CSR_BYTES + EDGE_BYTES; // ~174 MB

    const bool use_xb = (ws_size >= NEED_A);

    size_t off = 0;
    ushort_t* BT = (ushort_t*)(ws + off); off += BT_BYTES;
    ushort_t* xb = nullptr;
    if (use_xb) { xb = (ushort_t*)(ws + off); off += XB_BYTES; }
    ushort_t* H      = (ushort_t*)(ws + off); off += H_BYTES;
    int*      counts = (int*)(ws + off); off += CSR_BYTES;
    int*      offs   = (int*)(ws + off); off += CSR_BYTES;
    int*      cursor = (int*)(ws + off); off += CSR_BYTES;
    uint_t*   edges  = (uint_t*)(ws + off);

    prep_w_kernel<<<(N_COLS * IN_DIM + 255) / 256, 256, 0, stream>>>(Wself, rel, BT);
    hipMemsetAsync(counts, 0, (size_t)N_NODES * 4, stream);
    if (use_xb)
        conv_x_kernel<<<(N_NODES * IN_DIM / 8 + 255) / 256, 256, 0, stream>>>(x, xb);
    hist_kernel<<<(N_EDGES / 4 + 255) / 256, 256, 0, stream>>>(dst, counts);
    scan_kernel<<<1, 1024, 0, stream>>>(counts, offs, cursor, N_NODES);
    fill_kernel<<<(N_EDGES / 4 + 255) / 256, 256, 0, stream>>>(src, dst, cursor, edges);

    dim3 ggrid(3, (N_NODES + BM - 1) / BM);   // rel-block triple fastest; A stripe reused in L2/L3
    for (int p = 0; p < N_PHASE; ++p) {
        int c0 = p * CPH;
        if (use_xb)
            gemm_kernel<true><<<ggrid, 256, 0, stream>>>(xb, BT, H, N_NODES, c0);
        else
            gemm_kernel<false><<<ggrid, 256, 0, stream>>>(x, BT, H, N_NODES, c0);
        gather_kernel<<<(N_NODES + 3) / 4, 256, 0, stream>>>(H, offs, edges, out, c0);
    }
    ln_kernel<<<(N_NODES + 3) / 4, 256, 0, stream>>>(out, gamma, beta);
}

// Round 5
// 674.248 us; speedup vs baseline: 1.9380x; 1.2904x over previous
//
#include <hip/hip_runtime.h>
#include <hip/hip_bf16.h>

// ---------------- problem constants ----------------
#define N_NODES   100000
#define IN_DIM    256
#define OUT_DIM   256
#define N_REL     8
#define E_PER_REL 160000
#define N_EDGES   (N_REL * E_PER_REL)      // 1,280,000
#define N_COLS    ((N_REL + 1) * OUT_DIM)  // 2304 logical: rel blocks 0..7, self block 8
#define LN_EPS    1e-5f

// column phasing: 4 phases x 64 columns; H chunk holds 9 rel-blocks x 64 cols
#define CPH 64
#define N_PHASE 4
#define HC  (9 * CPH)   // 576 cols per H row

// CSR bucket pipeline
#define NB   256                 // buckets
#define NPB  391                 // nodes per bucket (256*391 = 100096 >= 100000)
#define ECHUNK 4096              // edges per WG in count/scatter passes
#define NWGE ((N_EDGES + ECHUNK - 1) / ECHUNK)   // 313

typedef unsigned short ushort_t;
typedef unsigned int   uint_t;

typedef __attribute__((ext_vector_type(8))) __bf16    bf16x8;
typedef __attribute__((ext_vector_type(4))) float     f32x4;

__device__ __forceinline__ ushort_t f2bf(float f) {
    uint_t x = __float_as_uint(f);
    x += 0x7FFFu + ((x >> 16) & 1u);   // round-to-nearest-even
    return (ushort_t)(x >> 16);
}
__device__ __forceinline__ float bf_lo(uint_t u) { return __uint_as_float(u << 16); }
__device__ __forceinline__ float bf_hi(uint_t u) { return __uint_as_float(u & 0xFFFF0000u); }

// ---------------- x fp32 -> bf16 (once) ----------------
__global__ void conv_x_kernel(const float* __restrict__ x, ushort_t* __restrict__ xb) {
    int i = blockIdx.x * 256 + threadIdx.x;         // one per 8 elements
    if (i >= N_NODES * IN_DIM / 8) return;
    const float4* p = (const float4*)x + (size_t)i * 2;
    float4 f0 = p[0], f1 = p[1];
    __hip_bfloat162 h0 = __float22bfloat162_rn(make_float2(f0.x, f0.y));
    __hip_bfloat162 h1 = __float22bfloat162_rn(make_float2(f0.z, f0.w));
    __hip_bfloat162 h2 = __float22bfloat162_rn(make_float2(f1.x, f1.y));
    __hip_bfloat162 h3 = __float22bfloat162_rn(make_float2(f1.z, f1.w));
    uint4 pv;
    __builtin_memcpy(&pv.x, &h0, 4);
    __builtin_memcpy(&pv.y, &h1, 4);
    __builtin_memcpy(&pv.z, &h2, 4);
    __builtin_memcpy(&pv.w, &h3, 4);
    *(uint4*)(xb + (size_t)i * 8) = pv;
}

// ---------------- prep: BT[n][k], n = r*256+c (r<8 rel, r==8 self) ----------------
__global__ void prep_w_kernel(const float* __restrict__ Wself, const float* __restrict__ rel,
                              ushort_t* __restrict__ BT) {
    int i = blockIdx.x * 256 + threadIdx.x;   // 0 .. 2304*256-1
    if (i >= N_COLS * IN_DIM) return;
    int n = i >> 8, k = i & 255;
    int r = n >> 8, c = n & 255;
    float v = (r < N_REL) ? rel[(((r << 8) + k) << 8) + c] : Wself[(k << 8) + c];
    BT[i] = f2bf(v);
}

// ---------------- CSR build: bucketed multi-split ----------------
// D1: per-WG LDS bucket histogram -> global bucket counts
__global__ __launch_bounds__(256) void count_buckets(const int* __restrict__ dst,
                                                     int* __restrict__ g_bcount) {
    __shared__ int cnt[NB];
    int tid = threadIdx.x;
    cnt[tid] = 0;
    __syncthreads();
    #pragma unroll
    for (int it = 0; it < 4; ++it) {
        int e = blockIdx.x * ECHUNK + it * 1024 + tid * 4;
        if (e < N_EDGES) {
            int4 d = *(const int4*)(dst + e);
            atomicAdd(&cnt[(uint_t)d.x / NPB], 1);
            atomicAdd(&cnt[(uint_t)d.y / NPB], 1);
            atomicAdd(&cnt[(uint_t)d.z / NPB], 1);
            atomicAdd(&cnt[(uint_t)d.w / NPB], 1);
        }
    }
    __syncthreads();
    if (cnt[tid]) atomicAdd(&g_bcount[tid], cnt[tid]);
}

// D2: scan 256 bucket counts -> bases + cursors
__global__ __launch_bounds__(256) void scan_buckets(const int* __restrict__ g_bcount,
                                                    int* __restrict__ g_bbase,
                                                    int* __restrict__ g_bcursor) {
    __shared__ int wsum[4];
    int tid = threadIdx.x, lane = tid & 63, w = tid >> 6;
    int val = g_bcount[tid];
    int x = val;
    #pragma unroll
    for (int d = 1; d < 64; d <<= 1) {
        int y = __shfl_up(x, d, 64);
        if (lane >= d) x += y;
    }
    if (lane == 63) wsum[w] = x;
    __syncthreads();
    if (tid == 0) {
        int a = 0;
        #pragma unroll
        for (int k = 0; k < 4; ++k) { int t = wsum[k]; wsum[k] = a; a += t; }
    }
    __syncthreads();
    int excl = wsum[w] + x - val;
    g_bbase[tid] = excl;
    g_bcursor[tid] = excl;
    if (tid == 255) g_bbase[256] = excl + val;
}

// D3: scatter 8B records into bucket-grouped tmp via per-WG reserved runs
__global__ __launch_bounds__(256) void scatter_buckets(const int* __restrict__ src,
                                                       const int* __restrict__ dst,
                                                       int* __restrict__ g_bcursor,
                                                       uint2* __restrict__ tmp) {
    __shared__ int cnt[NB];
    __shared__ int basec[NB];
    int tid = threadIdx.x;
    cnt[tid] = 0;
    __syncthreads();
    #pragma unroll
    for (int it = 0; it < 4; ++it) {
        int e = blockIdx.x * ECHUNK + it * 1024 + tid * 4;
        if (e < N_EDGES) {
            int4 d = *(const int4*)(dst + e);
            atomicAdd(&cnt[(uint_t)d.x / NPB], 1);
            atomicAdd(&cnt[(uint_t)d.y / NPB], 1);
            atomicAdd(&cnt[(uint_t)d.z / NPB], 1);
            atomicAdd(&cnt[(uint_t)d.w / NPB], 1);
        }
    }
    __syncthreads();
    basec[tid] = cnt[tid] ? atomicAdd(&g_bcursor[tid], cnt[tid]) : 0;
    __syncthreads();
    cnt[tid] = 0;
    __syncthreads();
    #pragma unroll
    for (int it = 0; it < 4; ++it) {
        int e = blockIdx.x * ECHUNK + it * 1024 + tid * 4;
        if (e < N_EDGES) {
            int4 d = *(const int4*)(dst + e);
            int4 s = *(const int4*)(src + e);
            uint_t relb = ((uint_t)e / E_PER_REL) << 20;   // e%4==0, E_PER_REL%4==0 -> uniform
            uint_t b0 = (uint_t)d.x / NPB, b1 = (uint_t)d.y / NPB;
            uint_t b2 = (uint_t)d.z / NPB, b3 = (uint_t)d.w / NPB;
            int p0 = basec[b0] + atomicAdd(&cnt[b0], 1);
            tmp[p0] = make_uint2((uint_t)d.x, (uint_t)s.x | relb);
            int p1 = basec[b1] + atomicAdd(&cnt[b1], 1);
            tmp[p1] = make_uint2((uint_t)d.y, (uint_t)s.y | relb);
            int p2 = basec[b2] + atomicAdd(&cnt[b2], 1);
            tmp[p2] = make_uint2((uint_t)d.z, (uint_t)s.z | relb);
            int p3 = basec[b3] + atomicAdd(&cnt[b3], 1);
            tmp[p3] = make_uint2((uint_t)d.w, (uint_t)s.w | relb);
        }
    }
}

// E: per-bucket node count + local scan -> offs slice + final edge scatter (bucket-local window)
__global__ __launch_bounds__(256) void build_csr(const uint2* __restrict__ tmp,
                                                 const int* __restrict__ g_bbase,
                                                 int* __restrict__ offs,
                                                 uint_t* __restrict__ edges) {
    __shared__ int cnt[NPB];
    __shared__ int sc[512];
    int b = blockIdx.x, tid = threadIdx.x;
    int node0 = b * NPB;
    int nn = min(NPB, N_NODES - node0);
    int r0 = g_bbase[b], r1 = g_bbase[b + 1];

    for (int i = tid; i < NPB; i += 256) cnt[i] = 0;
    __syncthreads();
    for (int i = r0 + tid; i < r1; i += 256) {
        uint2 rec = tmp[i];
        atomicAdd(&cnt[rec.x - node0], 1);
    }
    __syncthreads();
    // Hillis-Steele inclusive scan over 512 padded slots
    sc[tid]       = (tid < NPB) ? cnt[tid] : 0;
    sc[tid + 256] = (tid + 256 < NPB) ? cnt[tid + 256] : 0;
    __syncthreads();
    for (int d = 1; d < 512; d <<= 1) {
        int a  = (tid >= d) ? sc[tid - d] : 0;
        int a2 = (tid + 256 >= d) ? sc[tid + 256 - d] : 0;
        __syncthreads();
        sc[tid] += a; sc[tid + 256] += a2;
        __syncthreads();
    }
    // node offsets (exclusive) + cursors
    for (int i = tid; i < NPB; i += 256) {
        int ex = r0 + sc[i] - cnt[i];
        if (i < nn) offs[node0 + i] = ex;
        cnt[i] = ex;
    }
    if (b == NB - 1 && tid == 0) offs[N_NODES] = r1;
    __syncthreads();
    // scatter payloads within this bucket's window
    for (int i = r0 + tid; i < r1; i += 256) {
        uint2 rec = tmp[i];
        int pos = atomicAdd(&cnt[rec.x - node0], 1);
        edges[pos] = rec.y;
    }
}

// ---------------- phase GEMM: H[M][576] = X[M][256] @ BT[sel rows][256]^T ----------
// block: 128 rows x 3 rel-blocks x 64 cols. A staged once per kk, reused for 3 B tiles.
#define BM 128
#define BN 64
#define BK 64
#define KT 256
#define RB 3
#define EPAD 72   // epilogue LDS row stride (shorts): 64 + 8 pad

template <bool BF16X>
__global__ __launch_bounds__(256) void gemm_kernel(const void* __restrict__ Xv,
                                                   const ushort_t* __restrict__ B,
                                                   ushort_t* __restrict__ H,
                                                   int M, int c0) {
    // unified LDS: K-loop uses As (16KB) + 3x Bs (24KB); epilogue reuses front as 128x72 tile
    __shared__ ushort_t smem[BM * BK + RB * BN * BK];   // 40960 B
    ushort_t* As = smem;

    const int rb0 = blockIdx.x * RB;        // rel blocks rb0..rb0+2 (grid.x = 3 -> 0..8)
    const int m0  = blockIdx.y * BM;
    const int tid  = threadIdx.x;
    const int lane = tid & 63, w = tid >> 6;
    const int quad = lane >> 4, m16 = lane & 15;
    const int wm = (w & 1) * 64, wn = (w >> 1) * 32;

    f32x4 acc[RB][4][2];
    #pragma unroll
    for (int t = 0; t < RB; ++t)
        #pragma unroll
        for (int mi = 0; mi < 4; ++mi)
            #pragma unroll
            for (int ni = 0; ni < 2; ++ni)
                #pragma unroll
                for (int e = 0; e < 4; ++e) acc[t][mi][ni][e] = 0.f;

    for (int kk = 0; kk < KT; kk += BK) {
        // stage A: 1024 granules, 4 per thread (XOR-swizzled 16B granules)
        #pragma unroll
        for (int i = 0; i < 4; ++i) {
            int g = i * 256 + tid;
            int r = g >> 3, sc2 = g & 7, c = sc2 ^ (r & 7);
            int gr = m0 + r; if (gr >= M) gr = M - 1;
            if (BF16X) {
                const ushort_t* X = (const ushort_t*)Xv;
                *(uint4*)(&As[g * 8]) = *(const uint4*)(X + (size_t)gr * KT + kk + c * 8);
            } else {
                const float* X = (const float*)Xv;
                const float* sp = X + (size_t)gr * KT + kk + c * 8;
                float4 f0 = *(const float4*)sp;
                float4 f1 = *(const float4*)(sp + 4);
                __hip_bfloat162 h0 = __float22bfloat162_rn(make_float2(f0.x, f0.y));
                __hip_bfloat162 h1 = __float22bfloat162_rn(make_float2(f0.z, f0.w));
                __hip_bfloat162 h2 = __float22bfloat162_rn(make_float2(f1.x, f1.y));
                __hip_bfloat162 h3 = __float22bfloat162_rn(make_float2(f1.z, f1.w));
                uint4 pv;
                __builtin_memcpy(&pv.x, &h0, 4);
                __builtin_memcpy(&pv.y, &h1, 4);
                __builtin_memcpy(&pv.z, &h2, 4);
                __builtin_memcpy(&pv.w, &h3, 4);
                *(uint4*)(&As[g * 8]) = pv;
            }
        }
        // stage B tiles (bf16): 512 granules x 3, 2 per thread per tile
        #pragma unroll
        for (int t = 0; t < RB; ++t) {
            ushort_t* Bs = smem + BM * BK + t * BN * BK;
            #pragma unroll
            for (int i = 0; i < 2; ++i) {
                int g = i * 256 + tid;
                int r = g >> 3, sc2 = g & 7, c = sc2 ^ (r & 7);
                int nrow = (rb0 + t) * 256 + c0 + r;
                *(uint4*)(&Bs[g * 8]) = *(const uint4*)(B + (size_t)nrow * KT + kk + c * 8);
            }
        }
        __syncthreads();

        #pragma unroll
        for (int ks = 0; ks < BK; ks += 32) {
            int chunk = (ks >> 3) + quad;   // 0..7
            bf16x8 af[4];
            #pragma unroll
            for (int mi = 0; mi < 4; ++mi) {
                int row = wm + mi * 16 + m16;
                af[mi] = *(const bf16x8*)(&As[(row * 8 + (chunk ^ (row & 7))) * 8]);
            }
            #pragma unroll
            for (int t = 0; t < RB; ++t) {
                const ushort_t* Bs = smem + BM * BK + t * BN * BK;
                bf16x8 bfr[2];
                #pragma unroll
                for (int ni = 0; ni < 2; ++ni) {
                    int row = wn + ni * 16 + m16;
                    bfr[ni] = *(const bf16x8*)(&Bs[(row * 8 + (chunk ^ (row & 7))) * 8]);
                }
                #pragma unroll
                for (int mi = 0; mi < 4; ++mi)
                    #pragma unroll
                    for (int ni = 0; ni < 2; ++ni)
                        acc[t][mi][ni] = __builtin_amdgcn_mfma_f32_16x16x32_bf16(
                            af[mi], bfr[ni], acc[t][mi][ni], 0, 0, 0);
            }
        }
        __syncthreads();
    }

    // epilogue: per rel-block, transpose C through LDS, store coalesced 16B runs
    #pragma unroll
    for (int t = 0; t < RB; ++t) {
        // C/D layout: col = lane&15 (+ni*16+wn), row = quad*4 + reg (+mi*16+wm)
        #pragma unroll
        for (int mi = 0; mi < 4; ++mi)
            #pragma unroll
            for (int ni = 0; ni < 2; ++ni) {
                int col = wn + ni * 16 + m16;
                int rowb = wm + mi * 16 + quad * 4;
                #pragma unroll
                for (int rg = 0; rg < 4; ++rg)
                    smem[(rowb + rg) * EPAD + col] = f2bf(acc[t][mi][ni][rg]);
            }
        __syncthreads();
        #pragma unroll
        for (int i = 0; i < 4; ++i) {
            int cch = i * 256 + tid;            // 1024 chunks of 16B
            int row = cch >> 3, col8 = (cch & 7) * 8;
            int grow = m0 + row;
            if (grow < M) {
                uint4 v = *(const uint4*)(&smem[row * EPAD + col8]);
                *(uint4*)(H + (size_t)grow * HC + (rb0 + t) * CPH + col8) = v;
            }
        }
        __syncthreads();
    }
}

// ---------------- gather phase: one wave per node, 8 lanes x 16B per edge slot ----------
__global__ __launch_bounds__(256) void gather_kernel(const ushort_t* __restrict__ H,
                                                     const int* __restrict__ offs,
                                                     const uint_t* __restrict__ edges,
                                                     float* __restrict__ out, int c0) {
    int w = threadIdx.x >> 6, lane = threadIdx.x & 63;
    int node = blockIdx.x * 4 + w;
    if (node >= N_NODES) return;
    int grp = lane >> 3;          // edge slot 0..7
    int cs  = (lane & 7) * 8;     // col offset 0..56

    float a0 = 0.f, a1 = 0.f, a2 = 0.f, a3 = 0.f, a4 = 0.f, a5 = 0.f, a6 = 0.f, a7 = 0.f;
    if (grp == 7) {   // self block (col base 8*CPH = 512), counted once
        uint4 v = *(const uint4*)(H + (size_t)node * HC + 512 + cs);
        a0 += bf_lo(v.x); a1 += bf_hi(v.x); a2 += bf_lo(v.y); a3 += bf_hi(v.y);
        a4 += bf_lo(v.z); a5 += bf_hi(v.z); a6 += bf_lo(v.w); a7 += bf_hi(v.w);
    }
    int e0 = offs[node], e1 = offs[node + 1];
    for (int base = e0; base < e1; base += 32) {
        #pragma unroll
        for (int j = 0; j < 4; ++j) {
            int idx = base + j * 8 + grp;
            if (idx < e1) {
                uint_t r = edges[idx];
                uint4 v = *(const uint4*)(H + (size_t)(r & 0xFFFFFu) * HC + ((r >> 20) << 6) + cs);
                a0 += bf_lo(v.x); a1 += bf_hi(v.x); a2 += bf_lo(v.y); a3 += bf_hi(v.y);
                a4 += bf_lo(v.z); a5 += bf_hi(v.z); a6 += bf_lo(v.w); a7 += bf_hi(v.w);
            }
        }
    }
    // combine 8 edge-slot groups: xor over 8, 16, 32
    #pragma unroll
    for (int off = 8; off <= 32; off <<= 1) {
        a0 += __shfl_xor(a0, off, 64); a1 += __shfl_xor(a1, off, 64);
        a2 += __shfl_xor(a2, off, 64); a3 += __shfl_xor(a3, off, 64);
        a4 += __shfl_xor(a4, off, 64); a5 += __shfl_xor(a5, off, 64);
        a6 += __shfl_xor(a6, off, 64); a7 += __shfl_xor(a7, off, 64);
    }
    if (grp == 0) {
        float* op = out + (size_t)node * OUT_DIM + c0 + cs;
        *(float4*)op       = make_float4(a0, a1, a2, a3);
        *(float4*)(op + 4) = make_float4(a4, a5, a6, a7);
    }
}

// ---------------- in-place LayerNorm over d_out ----------------
__global__ __launch_bounds__(256) void ln_kernel(float* __restrict__ out,
                                                 const float* __restrict__ gamma,
                                                 const float* __restrict__ beta) {
    int w = threadIdx.x >> 6, lane = threadIdx.x & 63;
    int node = blockIdx.x * 4 + w;
    if (node >= N_NODES) return;
    int c4 = lane * 4;
    float4 v = *(const float4*)(out + (size_t)node * OUT_DIM + c4);
    float s = v.x + v.y + v.z + v.w;
    float q = v.x * v.x + v.y * v.y + v.z * v.z + v.w * v.w;
    #pragma unroll
    for (int off = 32; off > 0; off >>= 1) {
        s += __shfl_xor(s, off, 64);
        q += __shfl_xor(q, off, 64);
    }
    float mean = s * (1.f / 256.f);
    float var  = q * (1.f / 256.f) - mean * mean;
    float rstd = rsqrtf(var + LN_EPS);
    float4 g = *(const float4*)(gamma + c4);
    float4 b = *(const float4*)(beta + c4);
    float4 o;
    o.x = (v.x - mean) * rstd * g.x + b.x;
    o.y = (v.y - mean) * rstd * g.y + b.y;
    o.z = (v.z - mean) * rstd * g.z + b.z;
    o.w = (v.w - mean) * rstd * g.w + b.w;
    *(float4*)(out + (size_t)node * OUT_DIM + c4) = o;
}

// ---------------- launch ----------------
extern "C" void kernel_launch(void* const* d_in, const int* in_sizes, int n_in,
                              void* d_out, int out_size, void* d_ws, size_t ws_size,
                              hipStream_t stream) {
    const float* x     = (const float*)d_in[0];
    const int*   src   = (const int*)d_in[1];
    const int*   dst   = (const int*)d_in[2];
    const float* Wself = (const float*)d_in[3];
    const float* rel   = (const float*)d_in[4];
    const float* gamma = (const float*)d_in[5];
    const float* beta  = (const float*)d_in[6];
    float* out = (float*)d_out;

    char* ws = (char*)d_ws;
    constexpr size_t BT_BYTES   = (size_t)N_COLS * IN_DIM * 2;      // 1,179,648
    constexpr size_t XB_BYTES   = (size_t)N_NODES * IN_DIM * 2;     // 51,200,000
    constexpr size_t H_BYTES    = (size_t)N_NODES * HC * 2;         // 115,200,000
    constexpr size_t OFFS_BYTES = 400128;
    constexpr size_t BKT_BYTES  = 4096;                             // bcount/bbase/bcursor each
    constexpr size_t EDGE_BYTES = (size_t)N_EDGES * 4;              // 5,120,000
    // tmp (N_EDGES*8 = 10.24 MB) aliases the start of H: CSR build finishes before gemm writes H
    constexpr size_t NEED_A = BT_BYTES + XB_BYTES + H_BYTES + OFFS_BYTES + 3 * BKT_BYTES + EDGE_BYTES;

    const bool use_xb = (ws_size >= NEED_A);

    size_t off = 0;
    ushort_t* BT = (ushort_t*)(ws + off); off += BT_BYTES;
    ushort_t* xb = nullptr;
    if (use_xb) { xb = (ushort_t*)(ws + off); off += XB_BYTES; }
    ushort_t* H       = (ushort_t*)(ws + off); off += H_BYTES;
    uint2*    tmp     = (uint2*)H;                 // alias (dead before gemm)
    int*      offs    = (int*)(ws + off); off += OFFS_BYTES;
    int*      bcount  = (int*)(ws + off); off += BKT_BYTES;
    int*      bbase   = (int*)(ws + off); off += BKT_BYTES;
    int*      bcursor = (int*)(ws + off); off += BKT_BYTES;
    uint_t*   edges   = (uint_t*)(ws + off);

    prep_w_kernel<<<(N_COLS * IN_DIM + 255) / 256, 256, 0, stream>>>(Wself, rel, BT);
    hipMemsetAsync(bcount, 0, NB * 4, stream);
    if (use_xb)
        conv_x_kernel<<<(N_NODES * IN_DIM / 8 + 255) / 256, 256, 0, stream>>>(x, xb);
    count_buckets<<<NWGE, 256, 0, stream>>>(dst, bcount);
    scan_buckets<<<1, 256, 0, stream>>>(bcount, bbase, bcursor);
    scatter_buckets<<<NWGE, 256, 0, stream>>>(src, dst, bcursor, tmp);
    build_csr<<<NB, 256, 0, stream>>>(tmp, bbase, offs, edges);

    dim3 ggrid(3, (N_NODES + BM - 1) / BM);   // rel-block triple fastest; A stripe reused in L2/L3
    for (int p = 0; p < N_PHASE; ++p) {
        int c0 = p * CPH;
        if (use_xb)
            gemm_kernel<true><<<ggrid, 256, 0, stream>>>(xb, BT, H, N_NODES, c0);
        else
            gemm_kernel<false><<<ggrid, 256, 0, stream>>>(x, BT, H, N_NODES, c0);
        gather_kernel<<<(N_NODES + 3) / 4, 256, 0, stream>>>(H, offs, edges, out, c0);
    }
    ln_kernel<<<(N_NODES + 3) / 4, 256, 0, stream>>>(out, gamma, beta);
}